// Round 1
// 1739.027 us; speedup vs baseline: 1.3006x; 1.3006x over previous
//
#include <hip/hip_runtime.h>
#include <hip/hip_bf16.h>

// Problem dims (fixed by reference)
#define BB 2
#define LL 1024
#define DM 768
#define ED 1536
#define NTOK 2048        // BB*LL
#define DSTATE 16
#define DTRANK 48
#define VOCAB 32000

// chunked-scan config
#define CHUNK 64
#define NCHUNK (LL / CHUNK)   // 16

typedef unsigned short ushort_t;
typedef __attribute__((ext_vector_type(8))) short short8;   // 8 bf16 bits = 4 VGPRs (A/B frag)
typedef __attribute__((ext_vector_type(4))) float f32x4;    // C/D frag

__device__ __forceinline__ ushort_t f2bf(float f) {
    __hip_bfloat16 h = __float2bfloat16(f);
    return *(ushort_t*)&h;
}
__device__ __forceinline__ float silu(float x) { return x / (1.f + expf(-x)); }

// ---------------- embedding gather: x[t,:] = emb[ids[t],:] (f32) ----------------
__global__ void embed_kernel(const int* __restrict__ ids, const float* __restrict__ emb,
                             float* __restrict__ x) {
    int t = blockIdx.x;
    const float* src = emb + (size_t)ids[t] * DM;
    float* dst = x + (size_t)t * DM;
    for (int c = threadIdx.x; c < DM; c += blockDim.x) dst[c] = src[c];
}

// ---------------- rmsnorm over D (f32 in), emit bf16 for GEMM A-operand ----------------
__global__ void rmsnorm_kernel(const float* __restrict__ x, const float* __restrict__ w,
                               ushort_t* __restrict__ out, int D) {
    int t = blockIdx.x;
    const float* xr = x + (size_t)t * D;
    float ss = 0.f;
    for (int c = threadIdx.x; c < D; c += blockDim.x) { float v = xr[c]; ss += v * v; }
    #pragma unroll
    for (int o = 32; o > 0; o >>= 1) ss += __shfl_down(ss, o, 64);
    __shared__ float s[4];
    int wid = threadIdx.x >> 6;
    if ((threadIdx.x & 63) == 0) s[wid] = ss;
    __syncthreads();
    float rs = rsqrtf((s[0] + s[1] + s[2] + s[3]) / (float)D + 1e-5f);
    ushort_t* orow = out + (size_t)t * D;
    for (int c = threadIdx.x; c < D; c += blockDim.x)
        orow[c] = f2bf(xr[c] * rs * w[c]);
}

// ---------------- MFMA GEMM: out(MxN,f32) = A(MxK,bf16) * W(NxK,f32)^T [+ X(f32)] ----------
// 128x128 tile, BK=32, 4 waves each 4x4 of 16x16x32 mfma. M%128==0, N%128==0, K%32==0.
// B-staging converts fp32 weights -> bf16 into LDS on the fly.
template<bool RESID>
__global__ __launch_bounds__(256) void gemm_bt(const ushort_t* __restrict__ A,
                                               const float* __restrict__ W,
                                               const float* X,
                                               float* out,
                                               int M, int N, int K) {
    __shared__ __align__(16) ushort_t As[128][40];   // +8 pad: 80B row stride (16B-aligned rows)
    __shared__ __align__(16) ushort_t Bs[128][40];
    const int n0 = blockIdx.x * 128;
    const int m0 = blockIdx.y * 128;
    const int tid = threadIdx.x;
    const int w = tid >> 6, lane = tid & 63;
    const int wm = (w >> 1) * 64, wn = (w & 1) * 64;
    const int lrow = lane & 15, koff = (lane >> 4) * 8;
    const int sr = tid >> 2, sc = (tid & 3) * 8;

    f32x4 acc[4][4] = {};

    for (int k0 = 0; k0 < K; k0 += 32) {
        __syncthreads();
        // A: bf16 source, direct 16B copies (128 rows x 32 cols)
        *(uint4*)&As[sr][sc]      = *(const uint4*)&A[(size_t)(m0 + sr) * K + k0 + sc];
        *(uint4*)&As[sr + 64][sc] = *(const uint4*)&A[(size_t)(m0 + sr + 64) * K + k0 + sc];
        // B: fp32 source, float4 load -> 4x bf16 convert -> 8B LDS store
        #pragma unroll
        for (int it = 0; it < 4; ++it) {
            int chunk = tid + it * 256;            // 1024 chunks = 128 rows x 8 float4
            int row = chunk >> 3, col = (chunk & 7) * 4;
            float4 f = *(const float4*)&W[(size_t)(n0 + row) * K + k0 + col];
            ushort4 u;
            u.x = f2bf(f.x); u.y = f2bf(f.y); u.z = f2bf(f.z); u.w = f2bf(f.w);
            *(ushort4*)&Bs[row][col] = u;
        }
        __syncthreads();
        short8 af[4], bfr[4];
        #pragma unroll
        for (int t = 0; t < 4; ++t) af[t]  = *(const short8*)&As[wm + t * 16 + lrow][koff];
        #pragma unroll
        for (int t = 0; t < 4; ++t) bfr[t] = *(const short8*)&Bs[wn + t * 16 + lrow][koff];
        #pragma unroll
        for (int tm = 0; tm < 4; ++tm)
            #pragma unroll
            for (int tn = 0; tn < 4; ++tn)
                acc[tm][tn] = __builtin_amdgcn_mfma_f32_16x16x32_bf16(af[tm], bfr[tn], acc[tm][tn], 0, 0, 0);
    }

    const int kq4 = (lane >> 4) * 4;   // C/D: col = lane&15, row = (lane>>4)*4 + i  [verified m89/m91]
    #pragma unroll
    for (int tm = 0; tm < 4; ++tm) {
        #pragma unroll
        for (int tn = 0; tn < 4; ++tn) {
            const int c  = n0 + wn + tn * 16 + lrow;
            const int rb = m0 + wm + tm * 16 + kq4;
            #pragma unroll
            for (int i = 0; i < 4; ++i) {
                size_t off = (size_t)(rb + i) * N + c;
                float v = acc[tm][tn][i];
                if (RESID) v += X[off];
                out[off] = v;
            }
        }
    }
}

// ---------------- causal depthwise conv (D_CONV=4) + bias + silu ----------------
__global__ void conv_silu_kernel(const float* __restrict__ xz, const float* __restrict__ cw,
                                 const float* __restrict__ cb, float* __restrict__ xi) {
    int idx = blockIdx.x * blockDim.x + threadIdx.x;   // NTOK*ED
    int c = idx % ED;
    int t = idx / ED;
    int l = t % LL;
    float acc = cb[c];
    #pragma unroll
    for (int k = 0; k < 4; ++k) {
        int ls = l + k - 3;
        if (ls >= 0) acc += xz[(size_t)(t + k - 3) * (2 * ED) + c] * cw[c * 4 + k];
    }
    xi[idx] = silu(acc);
}

// ---------------- x_proj: dbc(NTOK,80) = xi(NTOK,ED) @ wx(80,ED)^T ----------------
__global__ void xproj_kernel(const float* __restrict__ xi, const float* __restrict__ wx,
                             float* __restrict__ dbc) {
    int t = blockIdx.x;
    __shared__ float sx[ED];
    const float* xr = xi + (size_t)t * ED;
    for (int c = threadIdx.x; c < ED; c += blockDim.x) sx[c] = xr[c];
    __syncthreads();
    int w = threadIdx.x >> 6, lane = threadIdx.x & 63;
    for (int j = w; j < DTRANK + 2 * DSTATE; j += 4) {
        const float* wr = wx + (size_t)j * ED;
        float s = 0.f;
        for (int k = lane; k < ED; k += 64) s += sx[k] * wr[k];
        #pragma unroll
        for (int o = 32; o > 0; o >>= 1) s += __shfl_down(s, o, 64);
        if (lane == 0) dbc[(size_t)t * 80 + j] = s;
    }
}

// ---------------- dt proj + softplus: delta(NTOK,ED) ----------------
__global__ void dtproj_kernel(const float* __restrict__ dbc, const float* __restrict__ wdt,
                              const float* __restrict__ bdt, float* __restrict__ delta) {
    int t = blockIdx.x;
    __shared__ float sdr[DTRANK];
    if (threadIdx.x < DTRANK) sdr[threadIdx.x] = dbc[(size_t)t * 80 + threadIdx.x];
    __syncthreads();
    for (int e = threadIdx.x; e < ED; e += blockDim.x) {
        const float* wr = wdt + (size_t)e * DTRANK;
        float acc = bdt[e];
        #pragma unroll
        for (int r = 0; r < DTRANK; ++r) acc += sdr[r] * wr[r];
        delta[(size_t)t * ED + e] = (acc > 20.f) ? acc : log1pf(expf(acc));
    }
}

// ---------------- chunked selective scan ----------------
// The recurrence h_t = dA_t*h_{t-1} + dBx_t is linear -> split L into NCHUNK chunks
// of CHUNK steps. Pass A scans each chunk from h=0 (16x parallelism vs monolithic),
// Pass B (tiny) combines chunk carries serially, Pass C adds the h_in correction:
//   y_t += C_t . (exp(Ae*cumsum(delta))  (.)  h_in[chunk]).
// Within-chunk math is identical to the reference step recurrence; the carry uses
// exp-of-sum == product-of-exps (float-rounding-level difference only).

// Pass A: wave = 4 channels x 16 states. lane: e = eb + (lane>>4), n = lane&15.
__global__ void scan_chunk_kernel(const float* __restrict__ delta, const float* __restrict__ xi,
                                  const float* __restrict__ dbc, const float* __restrict__ a_log,
                                  const float* __restrict__ skd, float* __restrict__ y,
                                  float* __restrict__ hfin, float* __restrict__ cA) {
    int b = blockIdx.z, c = blockIdx.y;
    int w = threadIdx.x >> 6, lane = threadIdx.x & 63;
    int n = lane & 15;
    int e = blockIdx.x * 16 + w * 4 + (lane >> 4);
    float Ae = -expf(a_log[e * DSTATE + n]);
    float skip = skd[e];
    float h = 0.f, sumdl = 0.f;
    size_t tb = (size_t)b * LL + (size_t)c * CHUNK;
    for (int l = 0; l < CHUNK; ++l) {
        size_t row = tb + l;
        float dl = delta[row * ED + e];
        float xv = xi[row * ED + e];
        float Bv = dbc[row * 80 + DTRANK + n];
        float Cv = dbc[row * 80 + DTRANK + DSTATE + n];
        float dA = __expf(dl * Ae);
        h = dA * h + dl * xv * Bv;
        sumdl += dl;
        float p = h * Cv;
        p += __shfl_xor(p, 1, 16);
        p += __shfl_xor(p, 2, 16);
        p += __shfl_xor(p, 4, 16);
        p += __shfl_xor(p, 8, 16);
        if (n == 0) y[row * ED + e] = p + skip * xv;   // local y + fused skip_D*xi
    }
    size_t sidx = (((size_t)b * NCHUNK + c) * ED + e) * DSTATE + n;
    hfin[sidx] = h;
    cA[sidx] = __expf(Ae * sumdl);
}

// Pass B: serial combine over NCHUNK carries; one thread per (b,e,n) state.
__global__ void chunk_carry_kernel(const float* __restrict__ hfin, const float* __restrict__ cA,
                                   float* __restrict__ hin) {
    int gid = blockIdx.x * blockDim.x + threadIdx.x;   // BB*ED*DSTATE threads
    int b = gid / (ED * DSTATE);
    int rem = gid - b * (ED * DSTATE);
    float h = 0.f;
    for (int c = 0; c < NCHUNK; ++c) {
        size_t idx = ((size_t)(b * NCHUNK + c)) * (ED * DSTATE) + rem;
        hin[idx] = h;                       // h entering chunk c
        h = cA[idx] * h + hfin[idx];        // carry to next chunk
    }
}

// Pass C: add correction for the incoming state (chunks 1..NCHUNK-1).
__global__ void scan_fixup_kernel(const float* __restrict__ delta, const float* __restrict__ dbc,
                                  const float* __restrict__ a_log, const float* __restrict__ hin,
                                  float* __restrict__ y) {
    int b = blockIdx.z, c = blockIdx.y + 1;
    int w = threadIdx.x >> 6, lane = threadIdx.x & 63;
    int n = lane & 15;
    int e = blockIdx.x * 16 + w * 4 + (lane >> 4);
    float Ae = -expf(a_log[e * DSTATE + n]);
    float h0 = hin[(((size_t)b * NCHUNK + c) * ED + e) * DSTATE + n];
    float sumdl = 0.f;
    size_t tb = (size_t)b * LL + (size_t)c * CHUNK;
    for (int l = 0; l < CHUNK; ++l) {
        size_t row = tb + l;
        float dl = delta[row * ED + e];
        sumdl += dl;
        float Cv = dbc[row * 80 + DTRANK + DSTATE + n];
        float p = __expf(Ae * sumdl) * h0 * Cv;
        p += __shfl_xor(p, 1, 16);
        p += __shfl_xor(p, 2, 16);
        p += __shfl_xor(p, 4, 16);
        p += __shfl_xor(p, 8, 16);
        if (n == 0) y[row * ED + e] += p;
    }
}

// ---------------- gate: yz = y_tot * silu(z), emit bf16 ----------------
__global__ void gate_kernel(const float* __restrict__ y, const float* __restrict__ xz,
                            ushort_t* __restrict__ yzb) {
    int idx = blockIdx.x * blockDim.x + threadIdx.x;   // NTOK*ED
    int c = idx % ED;
    int t = idx / ED;
    float z = xz[(size_t)t * (2 * ED) + ED + c];
    yzb[idx] = f2bf(y[idx] * silu(z));
}

extern "C" void kernel_launch(void* const* d_in, const int* in_sizes, int n_in,
                              void* d_out, int out_size, void* d_ws, size_t ws_size,
                              hipStream_t stream) {
    const int*   ids      = (const int*)d_in[0];
    const float* emb      = (const float*)d_in[1];
    const float* ln_w     = (const float*)d_in[2];
    const float* in_proj  = (const float*)d_in[3];
    const float* conv_w   = (const float*)d_in[4];
    const float* conv_b   = (const float*)d_in[5];
    const float* x_proj   = (const float*)d_in[6];
    const float* dt_w     = (const float*)d_in[7];
    const float* dt_b     = (const float*)d_in[8];
    const float* A_log    = (const float*)d_in[9];
    const float* skip_D   = (const float*)d_in[10];
    const float* out_proj = (const float*)d_in[11];
    const float* normf_w  = (const float*)d_in[12];
    const float* lm_head  = (const float*)d_in[13];

    char* ws = (char*)d_ws;
    float*    x     = (float*)(ws);                                   // NTOK*DM f32   (6.29 MB)
    ushort_t* h_bf  = (ushort_t*)(ws + 6291456);                      // NTOK*DM bf16  (3.15 MB)
    float*    xz    = (float*)(ws + 9437184);                         // NTOK*2ED f32  (25.2 MB)
    float*    xi    = (float*)(ws + 34603008);                        // NTOK*ED f32   (12.6 MB)
    float*    dbc   = (float*)(ws + 47185920);                        // NTOK*80 f32   (0.66 MB)
    float*    delta = (float*)(ws + 47841280);                        // NTOK*ED f32   (12.6 MB)
    float*    y     = (float*)(ws + 60424192);                        // NTOK*ED f32   (12.6 MB)
    ushort_t* yzb   = (ushort_t*)(ws + 73007104);                     // NTOK*ED bf16  (6.29 MB)
    float*    hfin  = (float*)(ws + 79298560);                        // BB*NC*ED*16 f32 (3.15 MB)
    float*    cAbuf = (float*)(ws + 82444288);                        // BB*NC*ED*16 f32 (3.15 MB)
    // hin aliases h_bf: exactly BB*NC*ED*16*4 = NTOK*DM*2 bytes, and h_bf is dead
    // between the in_proj GEMM (its consumer) and the next rmsnorm (its producer).
    float*    hin   = (float*)h_bf;
    const size_t WS_NEED = 85590016;                                  // ~85.6 MB total
    if (ws_size < WS_NEED) return;   // defensive: avoid OOB writes wedging the GPU

    embed_kernel<<<NTOK, 256, 0, stream>>>(ids, emb, x);

    for (int i = 0; i < 2; ++i) {
        const float* lw   = ln_w + (size_t)i * DM;
        const float* wip  = in_proj + (size_t)i * 2 * ED * DM;
        const float* cw   = conv_w + (size_t)i * ED * 4;
        const float* cb   = conv_b + (size_t)i * ED;
        const float* wx   = x_proj + (size_t)i * 80 * ED;
        const float* wdt  = dt_w + (size_t)i * ED * DTRANK;
        const float* bdt  = dt_b + (size_t)i * ED;
        const float* alog = A_log + (size_t)i * ED * DSTATE;
        const float* skd  = skip_D + (size_t)i * ED;
        const float* wo   = out_proj + (size_t)i * DM * ED;

        rmsnorm_kernel<<<NTOK, 256, 0, stream>>>(x, lw, h_bf, DM);
        gemm_bt<false><<<dim3(2 * ED / 128, NTOK / 128), 256, 0, stream>>>(
            h_bf, wip, nullptr, xz, NTOK, 2 * ED, DM);
        conv_silu_kernel<<<NTOK * ED / 256, 256, 0, stream>>>(xz, cw, cb, xi);
        xproj_kernel<<<NTOK, 256, 0, stream>>>(xi, wx, dbc);
        dtproj_kernel<<<NTOK, 256, 0, stream>>>(dbc, wdt, bdt, delta);
        scan_chunk_kernel<<<dim3(ED / 16, NCHUNK, BB), 256, 0, stream>>>(
            delta, xi, dbc, alog, skd, y, hfin, cAbuf);
        chunk_carry_kernel<<<BB * ED * DSTATE / 256, 256, 0, stream>>>(hfin, cAbuf, hin);
        scan_fixup_kernel<<<dim3(ED / 16, NCHUNK - 1, BB), 256, 0, stream>>>(
            delta, dbc, alog, hin, y);
        gate_kernel<<<NTOK * ED / 256, 256, 0, stream>>>(y, xz, yzb);
        gemm_bt<true><<<dim3(DM / 128, NTOK / 128), 256, 0, stream>>>(
            yzb, wo, x, x, NTOK, DM, ED);
    }

    rmsnorm_kernel<<<NTOK, 256, 0, stream>>>(x, normf_w, h_bf, DM);
    gemm_bt<false><<<dim3(VOCAB / 128, NTOK / 128), 256, 0, stream>>>(
        h_bf, lm_head, nullptr, (float*)d_out, NTOK, VOCAB, DM);
}

// Round 3
// 1609.291 us; speedup vs baseline: 1.4055x; 1.0806x over previous
//
#include <hip/hip_runtime.h>
#include <hip/hip_bf16.h>

// Problem dims (fixed by reference)
#define BB 2
#define LL 1024
#define DM 768
#define ED 1536
#define NTOK 2048        // BB*LL
#define DSTATE 16
#define DTRANK 48
#define VOCAB 32000

// chunked-scan config
#define CHUNK 64
#define NCHUNK (LL / CHUNK)   // 16

typedef unsigned short ushort_t;
typedef __attribute__((ext_vector_type(8))) short short8;   // 8 bf16 bits = 4 VGPRs (A/B frag)
typedef __attribute__((ext_vector_type(4))) float f32x4;    // C/D frag

__device__ __forceinline__ ushort_t f2bf(float f) {
    __hip_bfloat16 h = __float2bfloat16(f);
    return *(ushort_t*)&h;
}
__device__ __forceinline__ float silu(float x) { return x / (1.f + expf(-x)); }

// ---------------- embedding gather: x[t,:] = emb[ids[t],:] (f32) ----------------
__global__ void embed_kernel(const int* __restrict__ ids, const float* __restrict__ emb,
                             float* __restrict__ x) {
    int t = blockIdx.x;
    const float* src = emb + (size_t)ids[t] * DM;
    float* dst = x + (size_t)t * DM;
    for (int c = threadIdx.x; c < DM; c += blockDim.x) dst[c] = src[c];
}

// ---------------- rmsnorm over D (f32 in), emit bf16 for GEMM A-operand ----------------
__global__ void rmsnorm_kernel(const float* __restrict__ x, const float* __restrict__ w,
                               ushort_t* __restrict__ out, int D) {
    int t = blockIdx.x;
    const float* xr = x + (size_t)t * D;
    float ss = 0.f;
    for (int c = threadIdx.x; c < D; c += blockDim.x) { float v = xr[c]; ss += v * v; }
    #pragma unroll
    for (int o = 32; o > 0; o >>= 1) ss += __shfl_down(ss, o, 64);
    __shared__ float s[4];
    int wid = threadIdx.x >> 6;
    if ((threadIdx.x & 63) == 0) s[wid] = ss;
    __syncthreads();
    float rs = rsqrtf((s[0] + s[1] + s[2] + s[3]) / (float)D + 1e-5f);
    ushort_t* orow = out + (size_t)t * D;
    for (int c = threadIdx.x; c < D; c += blockDim.x)
        orow[c] = f2bf(xr[c] * rs * w[c]);
}

// ---------------- weight f32 -> bf16 (vectorized, count % 1024 == 0) ----------------
__global__ void w2bf_kernel(const float* __restrict__ w, ushort_t* __restrict__ o) {
    size_t i = ((size_t)blockIdx.x * blockDim.x + threadIdx.x) * 4;
    float4 f = *(const float4*)&w[i];
    ushort4 u;
    u.x = f2bf(f.x); u.y = f2bf(f.y); u.z = f2bf(f.z); u.w = f2bf(f.w);
    *(ushort4*)&o[i] = u;
}

// ---------------- MFMA GEMM: out(2048xN,f32) = A(2048xK,bf16) * Wb(NxK,bf16)^T [+ X] ----
// 128x128 tile, BK=32, linear LDS [128][32] (m97 read layout), register staging with
// loads issued before the barrier (load/compute overlap), 2 barriers per K-step.
// 4 waves, each 4x4 of 16x16x32 mfma. M fixed at 2048 (16 m-blocks).
// Grid: 1D, nwg = 16 * (N/128), nwg % 8 == 0 required (XCD swizzle, m-block fastest).
template<bool RESID>
__global__ __launch_bounds__(256) void gemm_bt2(const ushort_t* __restrict__ A,
                                                const ushort_t* __restrict__ Wb,
                                                const float* X, float* out,
                                                int N, int K) {
    __shared__ __align__(16) ushort_t As[128 * 32];
    __shared__ __align__(16) ushort_t Bs[128 * 32];
    // XCD-aware swizzle: blocks on one XCD get a contiguous f-range; m fastest
    // within it -> the 128-col W panel is L2-reused 16x, A stays L2/L3-resident.
    const int q = gridDim.x >> 3;                       // nwg % 8 == 0
    const int f = (blockIdx.x & 7) * q + (blockIdx.x >> 3);
    const int m0 = (f & 15) * 128;                      // M = 2048 -> 16 m-blocks
    const int n0 = (f >> 4) * 128;
    const int tid = threadIdx.x;
    const int w = tid >> 6, lane = tid & 63;
    const int wm = (w >> 1) * 64, wn = (w & 1) * 64;
    const int lrow = lane & 15, koff = (lane >> 4) * 8;
    // staging: thread tid covers (row = srow [+64], col = scol..scol+7), 16B each.
    // Linear LDS: element (row,col) at row*32+col; for this pattern that is tid*8.
    const int srow = tid >> 2, scol = (tid & 3) * 8;
    const ushort_t* Ab = A  + (size_t)(m0 + srow) * K + scol;
    const ushort_t* Bb = Wb + (size_t)(n0 + srow) * K + scol;

    f32x4 acc[4][4] = {};

    for (int k0 = 0; k0 < K; k0 += 32) {
        uint4 a0 = *(const uint4*)(Ab + k0);
        uint4 a1 = *(const uint4*)(Ab + (size_t)64 * K + k0);
        uint4 b0 = *(const uint4*)(Bb + k0);
        uint4 b1 = *(const uint4*)(Bb + (size_t)64 * K + k0);
        __syncthreads();   // previous tile's reads done before overwrite
        *(uint4*)&As[tid * 8]        = a0;
        *(uint4*)&As[2048 + tid * 8] = a1;
        *(uint4*)&Bs[tid * 8]        = b0;
        *(uint4*)&Bs[2048 + tid * 8] = b1;
        __syncthreads();
        short8 af[4], bfr[4];
        #pragma unroll
        for (int t = 0; t < 4; ++t) af[t]  = *(const short8*)&As[(wm + t * 16 + lrow) * 32 + koff];
        #pragma unroll
        for (int t = 0; t < 4; ++t) bfr[t] = *(const short8*)&Bs[(wn + t * 16 + lrow) * 32 + koff];
        #pragma unroll
        for (int tm = 0; tm < 4; ++tm)
            #pragma unroll
            for (int tn = 0; tn < 4; ++tn)
                acc[tm][tn] = __builtin_amdgcn_mfma_f32_16x16x32_bf16(af[tm], bfr[tn], acc[tm][tn], 0, 0, 0);
    }

    const int kq4 = (lane >> 4) * 4;   // C/D: col = lane&15, row = (lane>>4)*4 + i  [verified m89/m91]
    #pragma unroll
    for (int tm = 0; tm < 4; ++tm) {
        #pragma unroll
        for (int tn = 0; tn < 4; ++tn) {
            const int c  = n0 + wn + tn * 16 + lrow;
            const int rb = m0 + wm + tm * 16 + kq4;
            #pragma unroll
            for (int i = 0; i < 4; ++i) {
                size_t off = (size_t)(rb + i) * N + c;
                float v = acc[tm][tn][i];
                if (RESID) v += X[off];
                out[off] = v;
            }
        }
    }
}

// ---------------- causal depthwise conv (D_CONV=4) + bias + silu ----------------
__global__ void conv_silu_kernel(const float* __restrict__ xz, const float* __restrict__ cw,
                                 const float* __restrict__ cb, float* __restrict__ xi) {
    int idx = blockIdx.x * blockDim.x + threadIdx.x;   // NTOK*ED
    int c = idx % ED;
    int t = idx / ED;
    int l = t % LL;
    float acc = cb[c];
    #pragma unroll
    for (int k = 0; k < 4; ++k) {
        int ls = l + k - 3;
        if (ls >= 0) acc += xz[(size_t)(t + k - 3) * (2 * ED) + c] * cw[c * 4 + k];
    }
    xi[idx] = silu(acc);
}

// ---------------- x_proj: dbc(NTOK,80) = xi(NTOK,ED) @ wx(80,ED)^T ----------------
__global__ void xproj_kernel(const float* __restrict__ xi, const float* __restrict__ wx,
                             float* __restrict__ dbc) {
    int t = blockIdx.x;
    __shared__ float sx[ED];
    const float* xr = xi + (size_t)t * ED;
    for (int c = threadIdx.x; c < ED; c += blockDim.x) sx[c] = xr[c];
    __syncthreads();
    int w = threadIdx.x >> 6, lane = threadIdx.x & 63;
    for (int j = w; j < DTRANK + 2 * DSTATE; j += 4) {
        const float* wr = wx + (size_t)j * ED;
        float s = 0.f;
        for (int k = lane; k < ED; k += 64) s += sx[k] * wr[k];
        #pragma unroll
        for (int o = 32; o > 0; o >>= 1) s += __shfl_down(s, o, 64);
        if (lane == 0) dbc[(size_t)t * 80 + j] = s;
    }
}

// ---------------- dt proj + softplus: delta(NTOK,ED) ----------------
__global__ void dtproj_kernel(const float* __restrict__ dbc, const float* __restrict__ wdt,
                              const float* __restrict__ bdt, float* __restrict__ delta) {
    int t = blockIdx.x;
    __shared__ float sdr[DTRANK];
    if (threadIdx.x < DTRANK) sdr[threadIdx.x] = dbc[(size_t)t * 80 + threadIdx.x];
    __syncthreads();
    for (int e = threadIdx.x; e < ED; e += blockDim.x) {
        const float* wr = wdt + (size_t)e * DTRANK;
        float acc = bdt[e];
        #pragma unroll
        for (int r = 0; r < DTRANK; ++r) acc += sdr[r] * wr[r];
        delta[(size_t)t * ED + e] = (acc > 20.f) ? acc : log1pf(expf(acc));
    }
}

// ---------------- chunked selective scan ----------------
// h_t = dA_t*h_{t-1} + dBx_t is linear -> split L into NCHUNK chunks of CHUNK.
// Pass A scans each chunk from h=0, Pass B combines chunk carries serially,
// Pass C adds the incoming-state correction y_t += C_t.(exp(Ae*cumsum(dl)) (.) h_in).

// Pass A: wave = 4 channels x 16 states. lane: e = eb + (lane>>4), n = lane&15.
__global__ void scan_chunk_kernel(const float* __restrict__ delta, const float* __restrict__ xi,
                                  const float* __restrict__ dbc, const float* __restrict__ a_log,
                                  const float* __restrict__ skd, float* __restrict__ y,
                                  float* __restrict__ hfin, float* __restrict__ cA) {
    int b = blockIdx.z, c = blockIdx.y;
    int w = threadIdx.x >> 6, lane = threadIdx.x & 63;
    int n = lane & 15;
    int e = blockIdx.x * 16 + w * 4 + (lane >> 4);
    float Ae = -expf(a_log[e * DSTATE + n]);
    float skip = skd[e];
    float h = 0.f, sumdl = 0.f;
    size_t tb = (size_t)b * LL + (size_t)c * CHUNK;
    for (int l = 0; l < CHUNK; ++l) {
        size_t row = tb + l;
        float dl = delta[row * ED + e];
        float xv = xi[row * ED + e];
        float Bv = dbc[row * 80 + DTRANK + n];
        float Cv = dbc[row * 80 + DTRANK + DSTATE + n];
        float dA = __expf(dl * Ae);
        h = dA * h + dl * xv * Bv;
        sumdl += dl;
        float p = h * Cv;
        p += __shfl_xor(p, 1, 16);
        p += __shfl_xor(p, 2, 16);
        p += __shfl_xor(p, 4, 16);
        p += __shfl_xor(p, 8, 16);
        if (n == 0) y[row * ED + e] = p + skip * xv;   // local y + fused skip_D*xi
    }
    size_t sidx = (((size_t)b * NCHUNK + c) * ED + e) * DSTATE + n;
    hfin[sidx] = h;
    cA[sidx] = __expf(Ae * sumdl);
}

// Pass B: serial combine over NCHUNK carries; one thread per (b,e,n) state.
__global__ void chunk_carry_kernel(const float* __restrict__ hfin, const float* __restrict__ cA,
                                   float* __restrict__ hin) {
    int gid = blockIdx.x * blockDim.x + threadIdx.x;   // BB*ED*DSTATE threads
    int b = gid / (ED * DSTATE);
    int rem = gid - b * (ED * DSTATE);
    float h = 0.f;
    for (int c = 0; c < NCHUNK; ++c) {
        size_t idx = ((size_t)(b * NCHUNK + c)) * (ED * DSTATE) + rem;
        hin[idx] = h;                       // h entering chunk c
        h = cA[idx] * h + hfin[idx];        // carry to next chunk
    }
}

// Pass C: add correction for the incoming state (chunks 1..NCHUNK-1).
__global__ void scan_fixup_kernel(const float* __restrict__ delta, const float* __restrict__ dbc,
                                  const float* __restrict__ a_log, const float* __restrict__ hin,
                                  float* __restrict__ y) {
    int b = blockIdx.z, c = blockIdx.y + 1;
    int w = threadIdx.x >> 6, lane = threadIdx.x & 63;
    int n = lane & 15;
    int e = blockIdx.x * 16 + w * 4 + (lane >> 4);
    float Ae = -expf(a_log[e * DSTATE + n]);
    float h0 = hin[(((size_t)b * NCHUNK + c) * ED + e) * DSTATE + n];
    float sumdl = 0.f;
    size_t tb = (size_t)b * LL + (size_t)c * CHUNK;
    for (int l = 0; l < CHUNK; ++l) {
        size_t row = tb + l;
        float dl = delta[row * ED + e];
        sumdl += dl;
        float Cv = dbc[row * 80 + DTRANK + DSTATE + n];
        float p = __expf(Ae * sumdl) * h0 * Cv;
        p += __shfl_xor(p, 1, 16);
        p += __shfl_xor(p, 2, 16);
        p += __shfl_xor(p, 4, 16);
        p += __shfl_xor(p, 8, 16);
        if (n == 0) y[row * ED + e] += p;
    }
}

// ---------------- gate: yz = y_tot * silu(z), emit bf16 ----------------
__global__ void gate_kernel(const float* __restrict__ y, const float* __restrict__ xz,
                            ushort_t* __restrict__ yzb) {
    int idx = blockIdx.x * blockDim.x + threadIdx.x;   // NTOK*ED
    int c = idx % ED;
    int t = idx / ED;
    float z = xz[(size_t)t * (2 * ED) + ED + c];
    yzb[idx] = f2bf(y[idx] * silu(z));
}

extern "C" void kernel_launch(void* const* d_in, const int* in_sizes, int n_in,
                              void* d_out, int out_size, void* d_ws, size_t ws_size,
                              hipStream_t stream) {
    const int*   ids      = (const int*)d_in[0];
    const float* emb      = (const float*)d_in[1];
    const float* ln_w     = (const float*)d_in[2];
    const float* in_proj  = (const float*)d_in[3];
    const float* conv_w   = (const float*)d_in[4];
    const float* conv_b   = (const float*)d_in[5];
    const float* x_proj   = (const float*)d_in[6];
    const float* dt_w     = (const float*)d_in[7];
    const float* dt_b     = (const float*)d_in[8];
    const float* A_log    = (const float*)d_in[9];
    const float* skip_D   = (const float*)d_in[10];
    const float* out_proj = (const float*)d_in[11];
    const float* normf_w  = (const float*)d_in[12];
    const float* lm_head  = (const float*)d_in[13];

    char* ws = (char*)d_ws;
    float*    x     = (float*)(ws);                                   // NTOK*DM f32   (6.29 MB)
    ushort_t* h_bf  = (ushort_t*)(ws + 6291456);                      // NTOK*DM bf16  (3.15 MB)
    float*    xz    = (float*)(ws + 9437184);                         // NTOK*2ED f32  (25.2 MB)
    float*    xi    = (float*)(ws + 34603008);                        // NTOK*ED f32   (12.6 MB)
    float*    dbc   = (float*)(ws + 47185920);                        // NTOK*80 f32   (0.66 MB)
    float*    delta = (float*)(ws + 47841280);                        // NTOK*ED f32   (12.6 MB)
    float*    y     = (float*)(ws + 60424192);                        // NTOK*ED f32   (12.6 MB)
    ushort_t* yzb   = (ushort_t*)(ws + 73007104);                     // NTOK*ED bf16  (6.29 MB)
    float*    hfin  = (float*)(ws + 79298560);                        // BB*NC*ED*16 f32 (3.15 MB)
    float*    cAbuf = (float*)(ws + 82444288);                        // BB*NC*ED*16 f32 (3.15 MB)
    // hin aliases h_bf (same size, dead between the in_proj GEMM and next rmsnorm).
    float*    hin   = (float*)h_bf;
    // bf16 weight staging overlays dead regions:
    //  - in_proj bf16 (4.72 MB)  -> yzb region (dead until gate; gemm_in done by then)
    //  - out_proj bf16 (2.36 MB) -> xi region  (xi dead after scan pass A)
    //  - lm_head bf16 (49.2 MB)  -> xz+xi+delta regions (all dead after final gate)
    ushort_t* wip_bf = (ushort_t*)yzb;
    ushort_t* wo_bf  = (ushort_t*)xi;
    ushort_t* lmh_bf = (ushort_t*)xz;
    const size_t WS_NEED = 85590016;                                  // ~85.6 MB total
    if (ws_size < WS_NEED) return;   // defensive: avoid OOB writes wedging the GPU

    embed_kernel<<<NTOK, 256, 0, stream>>>(ids, emb, x);

    for (int i = 0; i < 2; ++i) {
        const float* lw   = ln_w + (size_t)i * DM;
        const float* wip  = in_proj + (size_t)i * 2 * ED * DM;
        const float* cw   = conv_w + (size_t)i * ED * 4;
        const float* cb   = conv_b + (size_t)i * ED;
        const float* wx   = x_proj + (size_t)i * 80 * ED;
        const float* wdt  = dt_w + (size_t)i * ED * DTRANK;
        const float* bdt  = dt_b + (size_t)i * ED;
        const float* alog = A_log + (size_t)i * ED * DSTATE;
        const float* skd  = skip_D + (size_t)i * ED;
        const float* wo   = out_proj + (size_t)i * DM * ED;

        rmsnorm_kernel<<<NTOK, 256, 0, stream>>>(x, lw, h_bf, DM);
        w2bf_kernel<<<2 * ED * DM / 1024, 256, 0, stream>>>(wip, wip_bf);
        gemm_bt2<false><<<16 * (2 * ED / 128), 256, 0, stream>>>(
            h_bf, wip_bf, nullptr, xz, 2 * ED, DM);
        conv_silu_kernel<<<NTOK * ED / 256, 256, 0, stream>>>(xz, cw, cb, xi);
        xproj_kernel<<<NTOK, 256, 0, stream>>>(xi, wx, dbc);
        dtproj_kernel<<<NTOK, 256, 0, stream>>>(dbc, wdt, bdt, delta);
        scan_chunk_kernel<<<dim3(ED / 16, NCHUNK, BB), 256, 0, stream>>>(
            delta, xi, dbc, alog, skd, y, hfin, cAbuf);
        chunk_carry_kernel<<<BB * ED * DSTATE / 256, 256, 0, stream>>>(hfin, cAbuf, hin);
        scan_fixup_kernel<<<dim3(ED / 16, NCHUNK - 1, BB), 256, 0, stream>>>(
            delta, dbc, alog, hin, y);
        w2bf_kernel<<<DM * ED / 1024, 256, 0, stream>>>(wo, wo_bf);
        gate_kernel<<<NTOK * ED / 256, 256, 0, stream>>>(y, xz, yzb);
        gemm_bt2<true><<<16 * (DM / 128), 256, 0, stream>>>(
            yzb, wo_bf, x, x, DM, ED);
    }

    rmsnorm_kernel<<<NTOK, 256, 0, stream>>>(x, normf_w, h_bf, DM);
    w2bf_kernel<<<VOCAB * DM / 1024, 256, 0, stream>>>(lm_head, lmh_bf);
    gemm_bt2<false><<<16 * (VOCAB / 128), 256, 0, stream>>>(
        h_bf, lmh_bf, nullptr, (float*)d_out, VOCAB, DM);
}

// Round 4
// 1344.697 us; speedup vs baseline: 1.6820x; 1.1968x over previous
//
#include <hip/hip_runtime.h>
#include <hip/hip_bf16.h>

// Problem dims (fixed by reference)
#define BB 2
#define LL 1024
#define DM 768
#define ED 1536
#define NTOK 2048        // BB*LL
#define DSTATE 16
#define DTRANK 48
#define VOCAB 32000

// chunked-scan config
#define CHUNK 64
#define NCHUNK (LL / CHUNK)   // 16

// xproj split-K config
#define XP_KS 8               // K splits (1536/8 = 192 per split)

typedef unsigned short ushort_t;
typedef __attribute__((ext_vector_type(8))) short short8;   // 8 bf16 bits = 4 VGPRs (A/B frag)
typedef __attribute__((ext_vector_type(4))) float f32x4;    // C/D frag

__device__ __forceinline__ ushort_t f2bf(float f) {
    __hip_bfloat16 h = __float2bfloat16(f);
    return *(ushort_t*)&h;
}
__device__ __forceinline__ float silu(float x) { return x / (1.f + expf(-x)); }

// ---------------- embedding gather: x[t,:] = emb[ids[t],:] (f32) ----------------
__global__ void embed_kernel(const int* __restrict__ ids, const float* __restrict__ emb,
                             float* __restrict__ x) {
    int t = blockIdx.x;
    const float* src = emb + (size_t)ids[t] * DM;
    float* dst = x + (size_t)t * DM;
    for (int c = threadIdx.x; c < DM; c += blockDim.x) dst[c] = src[c];
}

// ---------------- rmsnorm over D (f32 in), emit bf16 for GEMM A-operand ----------------
__global__ void rmsnorm_kernel(const float* __restrict__ x, const float* __restrict__ w,
                               ushort_t* __restrict__ out, int D) {
    int t = blockIdx.x;
    const float* xr = x + (size_t)t * D;
    float ss = 0.f;
    for (int c = threadIdx.x; c < D; c += blockDim.x) { float v = xr[c]; ss += v * v; }
    #pragma unroll
    for (int o = 32; o > 0; o >>= 1) ss += __shfl_down(ss, o, 64);
    __shared__ float s[4];
    int wid = threadIdx.x >> 6;
    if ((threadIdx.x & 63) == 0) s[wid] = ss;
    __syncthreads();
    float rs = rsqrtf((s[0] + s[1] + s[2] + s[3]) / (float)D + 1e-5f);
    ushort_t* orow = out + (size_t)t * D;
    for (int c = threadIdx.x; c < D; c += blockDim.x)
        orow[c] = f2bf(xr[c] * rs * w[c]);
}

// ---------------- weight f32 -> bf16 (vectorized, count % 1024 == 0) ----------------
__global__ void w2bf_kernel(const float* __restrict__ w, ushort_t* __restrict__ o) {
    size_t i = ((size_t)blockIdx.x * blockDim.x + threadIdx.x) * 4;
    float4 f = *(const float4*)&w[i];
    ushort4 u;
    u.x = f2bf(f.x); u.y = f2bf(f.y); u.z = f2bf(f.z); u.w = f2bf(f.w);
    *(ushort4*)&o[i] = u;
}

// ---------------- wx (80x1536 f32) -> padded bf16 panel (128x1536), zero rows>=80 ------
__global__ void wxpad_kernel(const float* __restrict__ wx, ushort_t* __restrict__ o) {
    int i = (blockIdx.x * blockDim.x + threadIdx.x) * 4;   // 128*1536 elems, row-major
    int row = i / ED;
    ushort4 u;
    if (row < 80) {
        float4 f = *(const float4*)&wx[(size_t)row * ED + (i % ED)];
        u.x = f2bf(f.x); u.y = f2bf(f.y); u.z = f2bf(f.z); u.w = f2bf(f.w);
    } else {
        u.x = u.y = u.z = u.w = 0;
    }
    *(ushort4*)&o[i] = u;
}

// ---------------- wdt (ED x DTRANK) -> wdtT (DTRANK x ED) for coalesced dtproj --------
__global__ void wdtT_kernel(const float* __restrict__ wdt, float* __restrict__ wdtT) {
    int id = blockIdx.x * blockDim.x + threadIdx.x;   // DTRANK*ED
    int r = id / ED, e = id % ED;
    wdtT[id] = wdt[(size_t)e * DTRANK + r];
}

// ---------------- zero dbc (NTOK*80 f32) before split-K atomics ----------------
__global__ void zero_dbc_kernel(float* __restrict__ dbc) {
    dbc[blockIdx.x * blockDim.x + threadIdx.x] = 0.f;
}

// ---------------- MFMA GEMM: out(2048xN,f32) = A(2048xK,bf16) * Wb(NxK,bf16)^T [+ X] ----
// 128x128 tile, BK=32, linear LDS [128][32] (m97 read layout), register staging with
// loads issued before the barrier (load/compute overlap), 2 barriers per K-step.
// 4 waves, each 4x4 of 16x16x32 mfma. M fixed at 2048 (16 m-blocks).
// Grid: 1D, nwg = 16 * (N/128), nwg % 8 == 0 required (XCD swizzle, m-block fastest).
template<bool RESID>
__global__ __launch_bounds__(256) void gemm_bt2(const ushort_t* __restrict__ A,
                                                const ushort_t* __restrict__ Wb,
                                                const float* X, float* out,
                                                int N, int K) {
    __shared__ __align__(16) ushort_t As[128 * 32];
    __shared__ __align__(16) ushort_t Bs[128 * 32];
    const int q = gridDim.x >> 3;                       // nwg % 8 == 0
    const int f = (blockIdx.x & 7) * q + (blockIdx.x >> 3);
    const int m0 = (f & 15) * 128;                      // M = 2048 -> 16 m-blocks
    const int n0 = (f >> 4) * 128;
    const int tid = threadIdx.x;
    const int w = tid >> 6, lane = tid & 63;
    const int wm = (w >> 1) * 64, wn = (w & 1) * 64;
    const int lrow = lane & 15, koff = (lane >> 4) * 8;
    const int srow = tid >> 2, scol = (tid & 3) * 8;
    const ushort_t* Ab = A  + (size_t)(m0 + srow) * K + scol;
    const ushort_t* Bb = Wb + (size_t)(n0 + srow) * K + scol;

    f32x4 acc[4][4] = {};

    for (int k0 = 0; k0 < K; k0 += 32) {
        uint4 a0 = *(const uint4*)(Ab + k0);
        uint4 a1 = *(const uint4*)(Ab + (size_t)64 * K + k0);
        uint4 b0 = *(const uint4*)(Bb + k0);
        uint4 b1 = *(const uint4*)(Bb + (size_t)64 * K + k0);
        __syncthreads();   // previous tile's reads done before overwrite
        *(uint4*)&As[tid * 8]        = a0;
        *(uint4*)&As[2048 + tid * 8] = a1;
        *(uint4*)&Bs[tid * 8]        = b0;
        *(uint4*)&Bs[2048 + tid * 8] = b1;
        __syncthreads();
        short8 af[4], bfr[4];
        #pragma unroll
        for (int t = 0; t < 4; ++t) af[t]  = *(const short8*)&As[(wm + t * 16 + lrow) * 32 + koff];
        #pragma unroll
        for (int t = 0; t < 4; ++t) bfr[t] = *(const short8*)&Bs[(wn + t * 16 + lrow) * 32 + koff];
        #pragma unroll
        for (int tm = 0; tm < 4; ++tm)
            #pragma unroll
            for (int tn = 0; tn < 4; ++tn)
                acc[tm][tn] = __builtin_amdgcn_mfma_f32_16x16x32_bf16(af[tm], bfr[tn], acc[tm][tn], 0, 0, 0);
    }

    const int kq4 = (lane >> 4) * 4;   // C/D: col = lane&15, row = (lane>>4)*4 + i
    #pragma unroll
    for (int tm = 0; tm < 4; ++tm) {
        #pragma unroll
        for (int tn = 0; tn < 4; ++tn) {
            const int c  = n0 + wn + tn * 16 + lrow;
            const int rb = m0 + wm + tm * 16 + kq4;
            #pragma unroll
            for (int i = 0; i < 4; ++i) {
                size_t off = (size_t)(rb + i) * N + c;
                float v = acc[tm][tn][i];
                if (RESID) v += X[off];
                out[off] = v;
            }
        }
    }
}

// ---------------- xproj as split-K MFMA: dbc(2048x80) += xi_bf(2048x1536) @ wxb^T ------
// Grid: 16 m-blocks x XP_KS splits = 128 blocks (%8==0 for swizzle). Single n-block
// (N padded 80->128); epilogue atomicAdds only c<80 into pre-zeroed dbc.
__global__ __launch_bounds__(256) void gemm_xp(const ushort_t* __restrict__ A,
                                               const ushort_t* __restrict__ Wb,
                                               float* __restrict__ out) {
    __shared__ __align__(16) ushort_t As[128 * 32];
    __shared__ __align__(16) ushort_t Bs[128 * 32];
    const int q = gridDim.x >> 3;
    const int f = (blockIdx.x & 7) * q + (blockIdx.x >> 3);
    const int m0 = (f & 15) * 128;
    const int ks = f >> 4;                         // 0..XP_KS-1
    const int kbeg = ks * (ED / XP_KS);            // 192-wide K slice
    const int kend = kbeg + ED / XP_KS;
    const int tid = threadIdx.x;
    const int w = tid >> 6, lane = tid & 63;
    const int wm = (w >> 1) * 64, wn = (w & 1) * 64;
    const int lrow = lane & 15, koff = (lane >> 4) * 8;
    const int srow = tid >> 2, scol = (tid & 3) * 8;
    const ushort_t* Ab = A  + (size_t)(m0 + srow) * ED + scol;
    const ushort_t* Bb = Wb + (size_t)srow * ED + scol;

    f32x4 acc[4][4] = {};

    for (int k0 = kbeg; k0 < kend; k0 += 32) {
        uint4 a0 = *(const uint4*)(Ab + k0);
        uint4 a1 = *(const uint4*)(Ab + (size_t)64 * ED + k0);
        uint4 b0 = *(const uint4*)(Bb + k0);
        uint4 b1 = *(const uint4*)(Bb + (size_t)64 * ED + k0);
        __syncthreads();
        *(uint4*)&As[tid * 8]        = a0;
        *(uint4*)&As[2048 + tid * 8] = a1;
        *(uint4*)&Bs[tid * 8]        = b0;
        *(uint4*)&Bs[2048 + tid * 8] = b1;
        __syncthreads();
        short8 af[4], bfr[4];
        #pragma unroll
        for (int t = 0; t < 4; ++t) af[t]  = *(const short8*)&As[(wm + t * 16 + lrow) * 32 + koff];
        #pragma unroll
        for (int t = 0; t < 4; ++t) bfr[t] = *(const short8*)&Bs[(wn + t * 16 + lrow) * 32 + koff];
        #pragma unroll
        for (int tm = 0; tm < 4; ++tm)
            #pragma unroll
            for (int tn = 0; tn < 4; ++tn)
                acc[tm][tn] = __builtin_amdgcn_mfma_f32_16x16x32_bf16(af[tm], bfr[tn], acc[tm][tn], 0, 0, 0);
    }

    const int kq4 = (lane >> 4) * 4;
    #pragma unroll
    for (int tm = 0; tm < 4; ++tm) {
        #pragma unroll
        for (int tn = 0; tn < 4; ++tn) {
            const int c  = wn + tn * 16 + lrow;
            if (c < 80) {
                const int rb = m0 + wm + tm * 16 + kq4;
                #pragma unroll
                for (int i = 0; i < 4; ++i)
                    atomicAdd(&out[(size_t)(rb + i) * 80 + c], acc[tm][tn][i]);
            }
        }
    }
}

// ---------------- causal depthwise conv (D_CONV=4) + bias + silu (f32 + bf16 out) -----
__global__ void conv_silu_kernel(const float* __restrict__ xz, const float* __restrict__ cw,
                                 const float* __restrict__ cb, float* __restrict__ xi,
                                 ushort_t* __restrict__ xib) {
    int idx = blockIdx.x * blockDim.x + threadIdx.x;   // NTOK*ED
    int c = idx % ED;
    int t = idx / ED;
    int l = t % LL;
    float acc = cb[c];
    #pragma unroll
    for (int k = 0; k < 4; ++k) {
        int ls = l + k - 3;
        if (ls >= 0) acc += xz[(size_t)(t + k - 3) * (2 * ED) + c] * cw[c * 4 + k];
    }
    float v = silu(acc);
    xi[idx] = v;
    xib[idx] = f2bf(v);
}

// ---------------- dt proj + softplus: delta(NTOK,ED), 4 tokens/block, wdtT coalesced ---
#define DTT 4
__global__ void dtproj_kernel(const float* __restrict__ dbc, const float* __restrict__ wdtT,
                              const float* __restrict__ bdt, float* __restrict__ delta) {
    int t0 = blockIdx.x * DTT;
    __shared__ float sdr[DTT][DTRANK];
    if (threadIdx.x < DTT * DTRANK)
        sdr[threadIdx.x / DTRANK][threadIdx.x % DTRANK] =
            dbc[(size_t)(t0 + threadIdx.x / DTRANK) * 80 + (threadIdx.x % DTRANK)];
    __syncthreads();
    for (int e = threadIdx.x; e < ED; e += blockDim.x) {
        float b = bdt[e];
        float a0 = b, a1 = b, a2 = b, a3 = b;
        #pragma unroll
        for (int r = 0; r < DTRANK; ++r) {
            float wv = wdtT[r * ED + e];           // consecutive lanes -> consecutive addrs
            a0 += sdr[0][r] * wv;
            a1 += sdr[1][r] * wv;
            a2 += sdr[2][r] * wv;
            a3 += sdr[3][r] * wv;
        }
        delta[(size_t)(t0 + 0) * ED + e] = (a0 > 20.f) ? a0 : log1pf(expf(a0));
        delta[(size_t)(t0 + 1) * ED + e] = (a1 > 20.f) ? a1 : log1pf(expf(a1));
        delta[(size_t)(t0 + 2) * ED + e] = (a2 > 20.f) ? a2 : log1pf(expf(a2));
        delta[(size_t)(t0 + 3) * ED + e] = (a3 > 20.f) ? a3 : log1pf(expf(a3));
    }
}

// ---------------- chunked selective scan ----------------
// h_t = dA_t*h_{t-1} + dBx_t is linear -> split L into NCHUNK chunks of CHUNK.
// Pass A scans each chunk from h=0, Pass B combines chunk carries serially,
// Pass C adds the incoming-state correction y_t += C_t.(exp(Ae*cumsum(dl)) (.) h_in).

// Pass A: wave = 4 channels x 16 states. lane: e = eb + (lane>>4), n = lane&15.
__global__ void scan_chunk_kernel(const float* __restrict__ delta, const float* __restrict__ xi,
                                  const float* __restrict__ dbc, const float* __restrict__ a_log,
                                  const float* __restrict__ skd, float* __restrict__ y,
                                  float* __restrict__ hfin, float* __restrict__ cA) {
    int b = blockIdx.z, c = blockIdx.y;
    int w = threadIdx.x >> 6, lane = threadIdx.x & 63;
    int n = lane & 15;
    int e = blockIdx.x * 16 + w * 4 + (lane >> 4);
    float Ae = -expf(a_log[e * DSTATE + n]);
    float skip = skd[e];
    float h = 0.f, sumdl = 0.f;
    size_t tb = (size_t)b * LL + (size_t)c * CHUNK;
    for (int l = 0; l < CHUNK; ++l) {
        size_t row = tb + l;
        float dl = delta[row * ED + e];
        float xv = xi[row * ED + e];
        float Bv = dbc[row * 80 + DTRANK + n];
        float Cv = dbc[row * 80 + DTRANK + DSTATE + n];
        float dA = __expf(dl * Ae);
        h = dA * h + dl * xv * Bv;
        sumdl += dl;
        float p = h * Cv;
        p += __shfl_xor(p, 1, 16);
        p += __shfl_xor(p, 2, 16);
        p += __shfl_xor(p, 4, 16);
        p += __shfl_xor(p, 8, 16);
        if (n == 0) y[row * ED + e] = p + skip * xv;   // local y + fused skip_D*xi
    }
    size_t sidx = (((size_t)b * NCHUNK + c) * ED + e) * DSTATE + n;
    hfin[sidx] = h;
    cA[sidx] = __expf(Ae * sumdl);
}

// Pass B: serial combine over NCHUNK carries; one thread per (b,e,n) state.
__global__ void chunk_carry_kernel(const float* __restrict__ hfin, const float* __restrict__ cA,
                                   float* __restrict__ hin) {
    int gid = blockIdx.x * blockDim.x + threadIdx.x;   // BB*ED*DSTATE threads
    int b = gid / (ED * DSTATE);
    int rem = gid - b * (ED * DSTATE);
    float h = 0.f;
    for (int c = 0; c < NCHUNK; ++c) {
        size_t idx = ((size_t)(b * NCHUNK + c)) * (ED * DSTATE) + rem;
        hin[idx] = h;                       // h entering chunk c
        h = cA[idx] * h + hfin[idx];        // carry to next chunk
    }
}

// Pass C: add correction for the incoming state (chunks 1..NCHUNK-1).
__global__ void scan_fixup_kernel(const float* __restrict__ delta, const float* __restrict__ dbc,
                                  const float* __restrict__ a_log, const float* __restrict__ hin,
                                  float* __restrict__ y) {
    int b = blockIdx.z, c = blockIdx.y + 1;
    int w = threadIdx.x >> 6, lane = threadIdx.x & 63;
    int n = lane & 15;
    int e = blockIdx.x * 16 + w * 4 + (lane >> 4);
    float Ae = -expf(a_log[e * DSTATE + n]);
    float h0 = hin[(((size_t)b * NCHUNK + c) * ED + e) * DSTATE + n];
    float sumdl = 0.f;
    size_t tb = (size_t)b * LL + (size_t)c * CHUNK;
    for (int l = 0; l < CHUNK; ++l) {
        size_t row = tb + l;
        float dl = delta[row * ED + e];
        sumdl += dl;
        float Cv = dbc[row * 80 + DTRANK + DSTATE + n];
        float p = __expf(Ae * sumdl) * h0 * Cv;
        p += __shfl_xor(p, 1, 16);
        p += __shfl_xor(p, 2, 16);
        p += __shfl_xor(p, 4, 16);
        p += __shfl_xor(p, 8, 16);
        if (n == 0) y[row * ED + e] += p;
    }
}

// ---------------- gate: yz = y_tot * silu(z), emit bf16 ----------------
__global__ void gate_kernel(const float* __restrict__ y, const float* __restrict__ xz,
                            ushort_t* __restrict__ yzb) {
    int idx = blockIdx.x * blockDim.x + threadIdx.x;   // NTOK*ED
    int c = idx % ED;
    int t = idx / ED;
    float z = xz[(size_t)t * (2 * ED) + ED + c];
    yzb[idx] = f2bf(y[idx] * silu(z));
}

extern "C" void kernel_launch(void* const* d_in, const int* in_sizes, int n_in,
                              void* d_out, int out_size, void* d_ws, size_t ws_size,
                              hipStream_t stream) {
    const int*   ids      = (const int*)d_in[0];
    const float* emb      = (const float*)d_in[1];
    const float* ln_w     = (const float*)d_in[2];
    const float* in_proj  = (const float*)d_in[3];
    const float* conv_w   = (const float*)d_in[4];
    const float* conv_b   = (const float*)d_in[5];
    const float* x_proj   = (const float*)d_in[6];
    const float* dt_w     = (const float*)d_in[7];
    const float* dt_b     = (const float*)d_in[8];
    const float* A_log    = (const float*)d_in[9];
    const float* skip_D   = (const float*)d_in[10];
    const float* out_proj = (const float*)d_in[11];
    const float* normf_w  = (const float*)d_in[12];
    const float* lm_head  = (const float*)d_in[13];

    char* ws = (char*)d_ws;
    float*    x     = (float*)(ws);                                   // NTOK*DM f32   (6.29 MB)
    ushort_t* h_bf  = (ushort_t*)(ws + 6291456);                      // NTOK*DM bf16  (3.15 MB)
    float*    xz    = (float*)(ws + 9437184);                         // NTOK*2ED f32  (25.2 MB)
    float*    xi    = (float*)(ws + 34603008);                        // NTOK*ED f32   (12.6 MB)
    float*    dbc   = (float*)(ws + 47185920);                        // NTOK*80 f32   (0.66 MB)
    float*    delta = (float*)(ws + 47841280);                        // NTOK*ED f32   (12.6 MB)
    float*    y     = (float*)(ws + 60424192);                        // NTOK*ED f32   (12.6 MB)
    ushort_t* yzb   = (ushort_t*)(ws + 73007104);                     // NTOK*ED bf16  (6.29 MB)
    float*    hfin  = (float*)(ws + 79298560);                        // BB*NC*ED*16 f32 (3.15 MB)
    float*    cAbuf = (float*)(ws + 82444288);                        // BB*NC*ED*16 f32 (3.15 MB)
    // Overlays (all live ranges disjoint, verified against launch order):
    float*    hin    = (float*)h_bf;        // dead between in_proj GEMM and next rmsnorm
    ushort_t* wip_bf = (ushort_t*)yzb;      // yzb dead until gate
    ushort_t* wo_bf  = (ushort_t*)xi;       // xi dead after scan pass A
    ushort_t* lmh_bf = (ushort_t*)xz;       // xz+... dead after final gate
    ushort_t* xib    = (ushort_t*)y;        // xi bf16 (6.29 MB); y written only after xproj
    ushort_t* wxb    = (ushort_t*)hfin;     // 128x1536 bf16 (393 KB); hfin written after xproj
    float*    wdtT   = (float*)cAbuf;       // 48x1536 f32 (295 KB); cAbuf written after dtproj
    const size_t WS_NEED = 85590016;                                  // ~85.6 MB total
    if (ws_size < WS_NEED) return;   // defensive: avoid OOB writes wedging the GPU

    embed_kernel<<<NTOK, 256, 0, stream>>>(ids, emb, x);

    for (int i = 0; i < 2; ++i) {
        const float* lw   = ln_w + (size_t)i * DM;
        const float* wip  = in_proj + (size_t)i * 2 * ED * DM;
        const float* cw   = conv_w + (size_t)i * ED * 4;
        const float* cb   = conv_b + (size_t)i * ED;
        const float* wx   = x_proj + (size_t)i * 80 * ED;
        const float* wdt  = dt_w + (size_t)i * ED * DTRANK;
        const float* bdt  = dt_b + (size_t)i * ED;
        const float* alog = A_log + (size_t)i * ED * DSTATE;
        const float* skd  = skip_D + (size_t)i * ED;
        const float* wo   = out_proj + (size_t)i * DM * ED;

        rmsnorm_kernel<<<NTOK, 256, 0, stream>>>(x, lw, h_bf, DM);
        w2bf_kernel<<<2 * ED * DM / 1024, 256, 0, stream>>>(wip, wip_bf);
        gemm_bt2<false><<<16 * (2 * ED / 128), 256, 0, stream>>>(
            h_bf, wip_bf, nullptr, xz, 2 * ED, DM);
        conv_silu_kernel<<<NTOK * ED / 256, 256, 0, stream>>>(xz, cw, cb, xi, xib);
        wxpad_kernel<<<128 * ED / 1024, 256, 0, stream>>>(wx, wxb);
        zero_dbc_kernel<<<NTOK * 80 / 256, 256, 0, stream>>>(dbc);
        gemm_xp<<<16 * XP_KS, 256, 0, stream>>>(xib, wxb, dbc);
        wdtT_kernel<<<DTRANK * ED / 256, 256, 0, stream>>>(wdt, wdtT);
        dtproj_kernel<<<NTOK / DTT, 256, 0, stream>>>(dbc, wdtT, bdt, delta);
        scan_chunk_kernel<<<dim3(ED / 16, NCHUNK, BB), 256, 0, stream>>>(
            delta, xi, dbc, alog, skd, y, hfin, cAbuf);
        chunk_carry_kernel<<<BB * ED * DSTATE / 256, 256, 0, stream>>>(hfin, cAbuf, hin);
        scan_fixup_kernel<<<dim3(ED / 16, NCHUNK - 1, BB), 256, 0, stream>>>(
            delta, dbc, alog, hin, y);
        w2bf_kernel<<<DM * ED / 1024, 256, 0, stream>>>(wo, wo_bf);
        gate_kernel<<<NTOK * ED / 256, 256, 0, stream>>>(y, xz, yzb);
        gemm_bt2<true><<<16 * (DM / 128), 256, 0, stream>>>(
            yzb, wo_bf, x, x, DM, ED);
    }

    rmsnorm_kernel<<<NTOK, 256, 0, stream>>>(x, normf_w, h_bf, DM);
    w2bf_kernel<<<VOCAB * DM / 1024, 256, 0, stream>>>(lm_head, lmh_bf);
    gemm_bt2<false><<<16 * (VOCAB / 128), 256, 0, stream>>>(
        h_bf, lmh_bf, nullptr, (float*)d_out, VOCAB, DM);
}